// Round 4
// baseline (105.094 us; speedup 1.0000x reference)
//
#include <hip/hip_runtime.h>
#include <hip/hip_bf16.h>
#include <math.h>

// PhaseMLP fully fused: interp-then-matmul == GEMM with c-scaled A:
//   y[b,o] = sum_{k,i} (c_k(b)*x[b,i]) * Wflat[k*K+i, o]
// Layer dependency is PER-ROW: one block carries its 16 rows through all
// 3 layers, activations in LDS. 2 launches:
//   1) weight transpose/convert fp32[4K,O] -> bf16 Wt[O,4K]
//   2) fused 3-layer kernel (256 blocks x 1024 threads = 4 waves/SIMD)
// R4 change: 4-way K-split per wave -> 4 independent MFMA chains (breaks the
// dependent-MFMA latency serialization R2/R3 both had) + depth-2/chain
// register prefetch (8 outstanding 16B B-loads per wave).

typedef __attribute__((ext_vector_type(8))) short bf16x8;
typedef __attribute__((ext_vector_type(4))) float f32x4;

#define STRIDE 2048  // bytes per LDS A-row: 128 segs x 16B (A0 uses 64 segs)

static __device__ __forceinline__ unsigned short f2bf(float f) {
  union { float f; unsigned int u; } v; v.f = f;
  unsigned int r = v.u + 0x7fffu + ((v.u >> 16) & 1u);  // RNE
  return (unsigned short)(r >> 16);
}

// Catmull-Rom basis coeffs in ABSOLUTE anchor order (c[0..3] for anchors 0..3)
static __device__ __forceinline__ void catmull(float ph, float c[4]) {
  float t = 4.0f * ph;
  float ft = floorf(t);
  int i1 = ((int)ft) & 3;
  float w = t - ft;
  float w2 = w * w, w3 = w2 * w;
  float r0 = -0.5f * w + w2 - 0.5f * w3;
  float r1 = 1.0f - 2.5f * w2 + 1.5f * w3;
  float r2 = 0.5f * w + 2.0f * w2 - 1.5f * w3;
  float r3 = -0.5f * w2 + 0.5f * w3;
  c[(i1 + 3) & 3] = r0;
  c[i1]           = r1;
  c[(i1 + 1) & 3] = r2;
  c[(i1 + 2) & 3] = r3;
}

// ---------------------------------------------------------------------------
// Prep: transpose+convert all three weight tensors (fp32 [4K,O] -> bf16 [O,4K])
// ---------------------------------------------------------------------------
__global__ void k_wt_all(const float* __restrict__ w0, const float* __restrict__ w1,
                         const float* __restrict__ w2, unsigned short* __restrict__ t0,
                         unsigned short* __restrict__ t1, unsigned short* __restrict__ t2) {
  __shared__ float tile[32][33];
  int bid = blockIdx.x;
  const float* W; unsigned short* T; int R, C, idx;
  if (bid < 128)      { W = w0; T = t0; R = 512;  C = 256; idx = bid; }
  else if (bid < 384) { W = w1; T = t1; R = 1024; C = 256; idx = bid - 128; }
  else                { W = w2; T = t2; R = 1024; C = 128; idx = bid - 384; }
  int ntc = C >> 5;
  int tr = (idx / ntc) << 5;
  int tc = (idx % ntc) << 5;
  int tx = threadIdx.x, ty = threadIdx.y;  // (32,8)
#pragma unroll
  for (int j = ty; j < 32; j += 8)
    tile[j][tx] = W[(size_t)(tr + j) * C + (tc + tx)];
  __syncthreads();
#pragma unroll
  for (int j = ty; j < 32; j += 8)
    T[(size_t)(tc + j) * R + (tr + tx)] = f2bf(tile[tx][j]);
}

// ---------------------------------------------------------------------------
// 4-way K-split GEMM task: one 16-col group, chunks [ck0, ck0+nc), nc%4==0.
// 4 independent MFMA chains (k-quarters) interleaved -> dependent-MFMA gap of
// 4 insts, 8 outstanding B-loads/wave. Chains summed in-register at the end.
// abase = bufIn + col*STRIDE (XOR-swizzled A rows); bp already offset by
// quad*8 + ck0*32 (ushort units). nc compile-time at all call sites.
// ---------------------------------------------------------------------------
static __device__ __forceinline__ f32x4 gemm_k4(const char* abase,
                                                const unsigned short* __restrict__ bp,
                                                int xr, int quad, int ck0, int nc) {
  const int q = nc >> 2;  // iters per chain
  f32x4 acc[4];
  bf16x8 pre[4][2];
#pragma unroll
  for (int c = 0; c < 4; ++c) {
    acc[c] = (f32x4){0.f, 0.f, 0.f, 0.f};
    pre[c][0] = *(const bf16x8*)(bp + (c * q) * 32);
    if (q > 1) pre[c][1] = *(const bf16x8*)(bp + (c * q + 1) * 32);
  }
#pragma unroll
  for (int i = 0; i < q; ++i) {
#pragma unroll
    for (int c = 0; c < 4; ++c) {
      bf16x8 bv = pre[c][i & 1];
      if (i + 2 < q) pre[c][i & 1] = *(const bf16x8*)(bp + (c * q + i + 2) * 32);
      int s = (ck0 + c * q + i) * 4 + quad;
      bf16x8 av = *(const bf16x8*)(abase + ((s ^ xr) << 4));
      acc[c] = __builtin_amdgcn_mfma_f32_16x16x32_bf16(av, bv, acc[c], 0, 0, 0);
    }
  }
  f32x4 r0 = acc[0] + acc[1];
  f32x4 r1 = acc[2] + acc[3];
  return r0 + r1;
}

// epilogue for layers 0/1: bias-mix, ELU, write 4 c-scaled bf16 copies to bufOut
static __device__ __forceinline__ void epi_mid(f32x4 acc, const float* __restrict__ bias,
                                               int N, int colg, int quad,
                                               const float cb[4][4], char* bufOut) {
  float bv0 = bias[colg], bv1 = bias[N + colg], bv2 = bias[2 * N + colg],
        bv3 = bias[3 * N + colg];
#pragma unroll
  for (int r = 0; r < 4; ++r) {
    int m = quad * 4 + r;
    float v = acc[r] + cb[r][0] * bv0 + cb[r][1] * bv1 + cb[r][2] * bv2 + cb[r][3] * bv3;
    float a = v > 0.0f ? v : (__expf(v) - 1.0f);  // ELU
#pragma unroll
    for (int k = 0; k < 4; ++k) {
      int idx = k * N + colg;
      int s = idx >> 3, j = idx & 7;
      *(unsigned short*)(bufOut + m * STRIDE + ((s ^ (m & 7)) << 4) + j * 2) =
          f2bf(cb[r][k] * a);
    }
  }
}

__global__ __launch_bounds__(1024, 4) void k_fused(
    const float* __restrict__ x, const float* __restrict__ phase,
    const unsigned short* __restrict__ Wt0, const float* __restrict__ b0,
    const unsigned short* __restrict__ Wt1, const float* __restrict__ b1,
    const unsigned short* __restrict__ Wt2, const float* __restrict__ b2,
    float* __restrict__ out) {
  __shared__ __align__(16) char bufA[16 * STRIDE];  // A0 / A2
  __shared__ __align__(16) char bufB[16 * STRIDE];  // A1, then layer-2 reduce buf

  const int tid = threadIdx.x;
  const int lane = tid & 63;
  const int wid = tid >> 6;     // 0..15
  const int col = lane & 15;
  const int quad = lane >> 4;
  const int xr = col & 7;
  const int m0 = blockIdx.x * 16;

  // per-lane Catmull coeffs for its 4 accumulator rows (m = quad*4+r)
  float cb[4][4];
#pragma unroll
  for (int r = 0; r < 4; ++r) catmull(phase[m0 + quad * 4 + r], cb[r]);

  // ---- build A0 (c-scaled bf16 x) into bufA: 16 rows x 64 segs = 1024 thr ----
  {
    int m = tid >> 6;   // row 0..15
    int s = tid & 63;   // 16B segment within row
    float cr[4];
    catmull(phase[m0 + m], cr);
    int kk = s >> 4;
    int i0 = (s & 15) << 3;
    const float* xp = x + (size_t)(m0 + m) * 128 + i0;
    float4 xa = *(const float4*)xp;
    float4 xbv = *(const float4*)(xp + 4);
    float cv = cr[kk];
    bf16x8 v;
    v[0] = (short)f2bf(cv * xa.x);  v[1] = (short)f2bf(cv * xa.y);
    v[2] = (short)f2bf(cv * xa.z);  v[3] = (short)f2bf(cv * xa.w);
    v[4] = (short)f2bf(cv * xbv.x); v[5] = (short)f2bf(cv * xbv.y);
    v[6] = (short)f2bf(cv * xbv.z); v[7] = (short)f2bf(cv * xbv.w);
    *(bf16x8*)(bufA + m * STRIDE + ((s ^ (m & 7)) << 4)) = v;
  }
  __syncthreads();

  // ---- layer 0: bufA (K=512) @ Wt0 -> bufB (A1), 16 waves x 16 cols
  {
    f32x4 acc = gemm_k4(bufA + col * STRIDE,
                        Wt0 + (size_t)(wid * 16 + col) * 512 + quad * 8,
                        xr, quad, 0, 16);
    epi_mid(acc, b0, 256, wid * 16 + col, quad, cb, bufB);
  }
  __syncthreads();

  // ---- layer 1: bufB (K=1024) @ Wt1 -> bufA (A2)
  {
    f32x4 acc = gemm_k4(bufB + col * STRIDE,
                        Wt1 + (size_t)(wid * 16 + col) * 1024 + quad * 8,
                        xr, quad, 0, 32);
    epi_mid(acc, b1, 256, wid * 16 + col, quad, cb, bufA);
  }
  __syncthreads();

  // ---- layer 2: bufA (K=1024) @ Wt2 -> out fp32. N=128: 8 col-grps x 2 k-halves
  {
    int colbase = (wid & 7) * 16;
    int kh = wid >> 3;
    f32x4 acc = gemm_k4(bufA + col * STRIDE,
                        Wt2 + (size_t)(colbase + col) * 1024 + quad * 8 + kh * 512,
                        xr, quad, kh * 16, 16);

    float* red = (float*)bufB;  // [8][16][17] fp32, overlaid (A1 is dead)
    if (wid >= 8) {
#pragma unroll
      for (int r = 0; r < 4; ++r)
        red[(wid - 8) * 272 + (quad * 4 + r) * 17 + col] = acc[r];
    }
    __syncthreads();
    if (wid < 8) {
      int colg = colbase + col;
      float bv0 = b2[colg], bv1 = b2[128 + colg], bv2 = b2[256 + colg],
            bv3 = b2[384 + colg];
#pragma unroll
      for (int r = 0; r < 4; ++r) {
        float v = acc[r] + red[wid * 272 + (quad * 4 + r) * 17 + col];
        v += cb[r][0] * bv0 + cb[r][1] * bv1 + cb[r][2] * bv2 + cb[r][3] * bv3;
        out[(size_t)(m0 + quad * 4 + r) * 128 + colg] = v;
      }
    }
  }
}

// ---------------------------------------------------------------------------
// ws layout: Wt0 @0 (256KB), Wt1 @256KB (512KB), Wt2 @768KB (256KB). 1 MB.
// ---------------------------------------------------------------------------
extern "C" void kernel_launch(void* const* d_in, const int* in_sizes, int n_in,
                              void* d_out, int out_size, void* d_ws, size_t ws_size,
                              hipStream_t stream) {
  const float* x     = (const float*)d_in[0];
  const float* phase = (const float*)d_in[1];
  const float* w0    = (const float*)d_in[2];
  const float* b0    = (const float*)d_in[3];
  const float* w1    = (const float*)d_in[4];
  const float* b1    = (const float*)d_in[5];
  const float* w2    = (const float*)d_in[6];
  const float* b2    = (const float*)d_in[7];
  float* out = (float*)d_out;

  char* ws = (char*)d_ws;
  unsigned short* Wt0 = (unsigned short*)ws;
  unsigned short* Wt1 = (unsigned short*)(ws + 262144);
  unsigned short* Wt2 = (unsigned short*)(ws + 262144 + 524288);

  k_wt_all<<<512, dim3(32, 8), 0, stream>>>(w0, w1, w2, Wt0, Wt1, Wt2);
  k_fused<<<256, 1024, 0, stream>>>(x, phase, Wt0, b0, Wt1, b1, Wt2, b2, out);
}